// Round 6
// baseline (936.921 us; speedup 1.0000x reference)
//
#include <hip/hip_runtime.h>

// SigmoidLoss: loss_ij = t_ij * log(clip(sigmoid(x_ij), eps, 1-eps));
// per row: max over positive labels, negate, weight; then mean over rows.
// log∘clip∘sigmoid is monotone => masked max over x commutes with the
// transform: find max x over positives, transform once per row.
// Pure streaming masked-max reduction => memory-bound (655 MB, one pass).
//
// R6: single fused kernel. Hot loop unchanged from R5 (wave-per-row, no LDS,
// deep MLP, nt loads). Final mean fused via last-block-done: release fence +
// device atomicAdd on a counter (zeroed by 4B hipMemsetAsync, capturable);
// last block acquire-fences and sums all 16384 row losses in fixed order
// (deterministic). Saves kernel-2 launch + inter-kernel gap.

#define NROWS   16384
#define NCOLS   5000
#define NVEC    (NCOLS / 4)   // 1250 = 19*64 + 34
#define EPSF    1e-6f
#define NBLOCKS 2048

typedef float fvec4 __attribute__((ext_vector_type(4)));
typedef int   ivec4 __attribute__((ext_vector_type(4)));

__global__ __launch_bounds__(256) void sigmoid_loss_fused_kernel(
    const float* __restrict__ inp,
    const int*   __restrict__ tgt,
    const float* __restrict__ w,
    float*       __restrict__ row_loss,
    unsigned int* __restrict__ done_ctr,
    float*       __restrict__ out)
{
    const int lane = threadIdx.x & 63;
    const int wid  = threadIdx.x >> 6;
    const int wave_global = blockIdx.x * 4 + wid;   // [0, 8192)
    const float NEG = -3.0e38f;

    #pragma unroll
    for (int rr = 0; rr < 2; ++rr) {
        const int row = wave_global * 2 + rr;       // [0, 16384), exact cover
        const fvec4* __restrict__ x4 = (const fvec4*)(inp + (size_t)row * NCOLS);
        const ivec4* __restrict__ t4 = (const ivec4*)(tgt + (size_t)row * NCOLS);

        float m = NEG;
        #pragma unroll
        for (int g = 0; g < 4; ++g) {
            fvec4 xv[5];
            ivec4 tv[5];
            // issue 10 loads back-to-back (deep MLP), then consume
            #pragma unroll
            for (int k = 0; k < 5; ++k) {
                const int idx = (g * 5 + k) * 64 + lane;
                if (idx < NVEC) {   // only predicated for chunk 19, lane>=34
                    xv[k] = __builtin_nontemporal_load(x4 + idx);
                    tv[k] = __builtin_nontemporal_load(t4 + idx);
                } else {
                    xv[k] = (fvec4)0.0f;
                    tv[k] = (ivec4)0;
                }
            }
            #pragma unroll
            for (int k = 0; k < 5; ++k) {
                m = fmaxf(m, (tv[k][0] > 0) ? xv[k][0] : NEG);
                m = fmaxf(m, (tv[k][1] > 0) ? xv[k][1] : NEG);
                m = fmaxf(m, (tv[k][2] > 0) ? xv[k][2] : NEG);
                m = fmaxf(m, (tv[k][3] > 0) ? xv[k][3] : NEG);
            }
        }

        // wave (64-lane) max reduction — register-only, no barrier
        #pragma unroll
        for (int off = 32; off > 0; off >>= 1)
            m = fmaxf(m, __shfl_xor(m, off, 64));

        if (lane == 0) {
            float loss = 0.0f;
            if (m > -1.0e38f) {  // row has at least one positive
                float p = 1.0f / (1.0f + __expf(-m));
                p = fminf(fmaxf(p, EPSF), 1.0f - EPSF);
                loss = -logf(p) * w[row];
            }
            row_loss[row] = loss;  // every row written => no ws pre-zero needed
        }
    }

    // ---- last-block-done fused reduction ----
    __shared__ bool amLast;
    __threadfence();   // agent-scope release: row_loss visible device-wide
    __syncthreads();   // whole block's stores + fences done
    if (threadIdx.x == 0) {
        unsigned int old = atomicAdd(done_ctr, 1u);   // device-scope
        amLast = (old == NBLOCKS - 1u);
    }
    __syncthreads();

    if (amLast) {
        __threadfence();   // acquire: invalidate stale cache lines
        // 16384 floats = 4096 fvec4; 256 threads x 16 fvec4, fixed order.
        const fvec4* __restrict__ rl4 = (const fvec4*)row_loss;
        float s = 0.0f;
        #pragma unroll
        for (int j = 0; j < 16; ++j) {
            fvec4 v = rl4[threadIdx.x + j * 256];
            s += (v[0] + v[1]) + (v[2] + v[3]);
        }
        #pragma unroll
        for (int off = 32; off > 0; off >>= 1)
            s += __shfl_xor(s, off, 64);

        __shared__ float ssum[4];
        if (lane == 0) ssum[wid] = s;
        __syncthreads();
        if (threadIdx.x == 0)
            out[0] = (ssum[0] + ssum[1] + ssum[2] + ssum[3]) / (float)NROWS;
    }
}

extern "C" void kernel_launch(void* const* d_in, const int* in_sizes, int n_in,
                              void* d_out, int out_size, void* d_ws, size_t ws_size,
                              hipStream_t stream) {
    const float* inp = (const float*)d_in[0];
    const int*   tgt = (const int*)d_in[1];
    const float* w   = (const float*)d_in[2];
    float* row_loss  = (float*)d_ws;                       // 64 KB
    unsigned int* done_ctr = (unsigned int*)((char*)d_ws + 65536);
    float* out       = (float*)d_out;

    // zero the completion counter (graph-capturable async memset, 4 bytes)
    hipMemsetAsync(done_ctr, 0, sizeof(unsigned int), stream);
    sigmoid_loss_fused_kernel<<<NBLOCKS, 256, 0, stream>>>(
        inp, tgt, w, row_loss, done_ctr, out);
}